// Round 2
// baseline (214.974 us; speedup 1.0000x reference)
//
#include <hip/hip_runtime.h>

// ---------------------------------------------------------------------------
// MultiHeadedAttention: B=2, S=2048, Dm=1024, H=16, hd=64
// R5: issue-bound attention -> amortize per-row overhead:
//  - each wave owns 32 q-rows (two 16-row MFMA groups); K/V LDS fragments,
//    staging, addressing and loop overhead shared across both groups
//  - 256-thread blocks (4 waves, 128 q-rows), grid (16,NH,B); co-resident
//    block pairs (qt, 15-qt) keep per-CU tile count constant (34)
//  - score scale*log2e folded into W_in Q-columns (f32 mul pre-bf16-round):
//    removes 16 v_mul per wave-tile
//  - LDS fragment reads via 4 base pointers + constant offsets
//  - double-buffered K/V staging, ONE barrier per key-tile
//  - S^T=mfma(K,Q), O^T=mfma(V^T,P^T), P transpose via ds_bpermute
// ---------------------------------------------------------------------------

typedef __bf16 bf16x8 __attribute__((ext_vector_type(8)));
typedef float f32x4 __attribute__((ext_vector_type(4)));
typedef int i32x4 __attribute__((ext_vector_type(4)));

#define B_   2
#define S_   2048
#define DM   1024
#define NH   16
#define HD   64
#define N3   3072
#define M_   4096   // B_*S_

// 0.125 (1/sqrt(64)) * log2(e) -- folded into W_in Q-columns on host side
#define SCALE_LOG2E 0.180336884f

__device__ __forceinline__ unsigned short f2bf(float f) {
  unsigned int u = __float_as_uint(f);
  u += 0x7fffu + ((u >> 16) & 1u);   // round-to-nearest-even
  return (unsigned short)(u >> 16);
}

__device__ __forceinline__ void gload_lds16(void* lds, const void* g) {
  __builtin_amdgcn_global_load_lds(
      (__attribute__((address_space(1))) void*)g,
      (__attribute__((address_space(3))) void*)lds, 16, 0, 0);
}

// ---------------- fp32 -> bf16 elementwise (query) -------------------------
__global__ __launch_bounds__(256) void f32_to_bf16_vec(
    const float4* __restrict__ in, unsigned short* __restrict__ out, int n4) {
  int i = blockIdx.x * 256 + threadIdx.x;
  if (i < n4) {
    float4 v = in[i];
    ushort4 o;
    o.x = f2bf(v.x); o.y = f2bf(v.y); o.z = f2bf(v.z); o.w = f2bf(v.w);
    *(ushort4*)(&out[(size_t)i * 4]) = o;
  }
}

// ------- fp32 [R][C] -> bf16 [C][R] transpose (weights), row-scaled --------
// output rows < scale_rows get multiplied by scale (f32, before rounding)
__global__ __launch_bounds__(256) void transpose_f32_bf16(
    const float* __restrict__ in, unsigned short* __restrict__ out, int R, int C,
    int scale_rows, float scale) {
  __shared__ float tile[32][33];
  const int tx = threadIdx.x, ty = threadIdx.y;
  const int x = blockIdx.x * 32 + tx;
  const int y0 = blockIdx.y * 32;
#pragma unroll
  for (int j = 0; j < 32; j += 8)
    tile[ty + j][tx] = in[(size_t)(y0 + ty + j) * C + x];
  __syncthreads();
  const int ox = y0 + tx;
  const int oy0 = blockIdx.x * 32;
#pragma unroll
  for (int j = 0; j < 32; j += 8) {
    const int orow = oy0 + ty + j;
    float v = tile[tx][ty + j];
    if (orow < scale_rows) v *= scale;
    out[(size_t)orow * R + ox] = f2bf(v);
  }
}

// ---------------- V slice of qkv -> vT[b][h][d][s] (bf16) ------------------
__global__ __launch_bounds__(256) void transpose_v(
    const unsigned short* __restrict__ qkv, unsigned short* __restrict__ vT) {
  __shared__ unsigned short tile[32][33];
  const int tx = threadIdx.x, ty = threadIdx.y;
  const int c0 = blockIdx.x * 32;   // v-dim 0..1023
  const int r0 = blockIdx.y * 32;   // token 0..4095
#pragma unroll
  for (int j = 0; j < 32; j += 8)
    tile[ty + j][tx] = qkv[(size_t)(r0 + ty + j) * N3 + 2 * DM + c0 + tx];
  __syncthreads();
  const int b = r0 >> 11;
  const int srow = (r0 & 2047);
  const int head = c0 >> 6;
#pragma unroll
  for (int j = 0; j < 32; j += 8) {
    const int d = (c0 & 63) + ty + j;
    vT[(size_t)((b * NH + head) * HD + d) * S_ + srow + tx] = tile[tx][ty + j];
  }
}

// ---------------- GEMM: C[M][N] = A[M][K] @ Bt[N][K]^T ---------------------
template <int OUT_BF16>
__global__ __launch_bounds__(256) void gemm_abt(
    const unsigned short* __restrict__ A, const unsigned short* __restrict__ Bt,
    void* __restrict__ Cv, int M, int N, int K) {
  __shared__ __align__(16) unsigned short a_sm[128 * 32];
  __shared__ __align__(16) unsigned short b_sm[128 * 32];
  const int tid = threadIdx.x;
  const int lane = tid & 63, wave = tid >> 6;
  const int quad = lane >> 4, l15 = lane & 15;
  const int row0 = blockIdx.y * 128, col0 = blockIdx.x * 128;
  const int wm = (wave >> 1) * 64, wn = (wave & 1) * 64;

  f32x4 acc[4][4];
#pragma unroll
  for (int i = 0; i < 4; i++)
#pragma unroll
    for (int j = 0; j < 4; j++) acc[i][j] = (f32x4){0.f, 0.f, 0.f, 0.f};

  const int e0 = tid * 8;

  for (int k0 = 0; k0 < K; k0 += 32) {
    __syncthreads();
#pragma unroll
    for (int i = 0; i < 2; i++) {
      int e = e0 + i * 2048;
      int r = e >> 5, c = e & 31;
      gload_lds16(&a_sm[e], &A[(size_t)(row0 + r) * K + k0 + c]);
      gload_lds16(&b_sm[e], &Bt[(size_t)(col0 + r) * K + k0 + c]);
    }
    __syncthreads();

    bf16x8 af[4], bfb[4];
#pragma unroll
    for (int i = 0; i < 4; i++) {
      af[i]  = *(const bf16x8*)&a_sm[(wm + i * 16 + l15) * 32 + quad * 8];
      bfb[i] = *(const bf16x8*)&b_sm[(wn + i * 16 + l15) * 32 + quad * 8];
    }
#pragma unroll
    for (int i = 0; i < 4; i++)
#pragma unroll
      for (int j = 0; j < 4; j++)
        acc[i][j] = __builtin_amdgcn_mfma_f32_16x16x32_bf16(af[i], bfb[j], acc[i][j], 0, 0, 0);
  }

#pragma unroll
  for (int i = 0; i < 4; i++) {
#pragma unroll
    for (int j = 0; j < 4; j++) {
#pragma unroll
      for (int r = 0; r < 4; r++) {
        const int row = row0 + wm + i * 16 + quad * 4 + r;
        const int col = col0 + wn + j * 16 + l15;
        const float v = acc[i][j][r];
        if (OUT_BF16)
          ((unsigned short*)Cv)[(size_t)row * N + col] = f2bf(v);
        else
          ((float*)Cv)[(size_t)row * N + col] = v;
      }
    }
  }
}

// ---------------- fused causal attention v5 --------------------------------
// grid (16, NH, B), 256 threads (4 waves). Wave owns 32 q-rows as two
// 16-row groups (g=0: qt*128+w*16, g=1: +64). K/V fragments + staging are
// shared by both groups -> ~40% fewer issue slots per q-row.
// Group 0 skips the last key tile (t=nt-1); group g's diagonal tile is
// t = nt-2+g. Scores arrive pre-scaled by 0.125*log2e (folded into W_in).
__global__ __launch_bounds__(256, 2) void attn_fused5(
    const unsigned short* __restrict__ qkv,
    const unsigned short* __restrict__ vT,
    unsigned short* __restrict__ attnout) {
  const int h = blockIdx.y, b = blockIdx.z;
  // reverse-pair qt across batch so co-resident blocks balance causal work
  const int qt = (b == 0) ? blockIdx.x : (15 - blockIdx.x);
  const int tid = threadIdx.x;
  const int lane = tid & 63, wave = tid >> 6;   // wave 0..3
  const int quad = lane >> 4, l15 = lane & 15;
  const int sw = l15 & 7;

  __shared__ __align__(16) unsigned short k_sm[2 * 4096];   // [buf][64 keys][64 d]
  __shared__ __align__(16) unsigned short vt_sm[2 * 4096];  // [buf][64 d][64 keys]

  const int wrow0 = qt * 128 + wave * 16;   // group-0 base row
  const int qrow0 = wrow0 + l15;
  const int qrow1 = qrow0 + 64;

  // Q fragments for both groups (B-operand for S^T)
  bf16x8 qf[2][2];
  {
    const unsigned short* qp0 = qkv + (size_t)(b * S_ + qrow0) * N3 + h * HD + quad * 8;
    qf[0][0] = *(const bf16x8*)qp0;
    qf[0][1] = *(const bf16x8*)(qp0 + 32);
    const unsigned short* qp1 = qp0 + (size_t)64 * N3;
    qf[1][0] = *(const bf16x8*)qp1;
    qf[1][1] = *(const bf16x8*)(qp1 + 32);
  }

  f32x4 o[2][4];   // O^T accumulators per group
#pragma unroll
  for (int g = 0; g < 2; g++)
#pragma unroll
    for (int n = 0; n < 4; n++) o[g][n] = (f32x4){0.f, 0.f, 0.f, 0.f};
  float lsum[2] = {0.f, 0.f};

  // staging: 256 threads, each stages rows r0s and r0s+32 (16B each)
  // phys chunk tid&7 holds logical chunk (tid&7)^(r0s&7) (XOR swizzle)
  const int r0s = tid >> 3;                       // 0..31
  const int gch = ((tid & 7) ^ (r0s & 7)) * 8;
  const unsigned short* kgb = qkv + (size_t)(b * S_ + r0s) * N3 + DM + h * HD + gch;
  const unsigned short* vgb = vT + (size_t)((b * NH + h) * HD + r0s) * S_ + gch;

  // bpermute pull addresses (byte addr = src_lane*4), quad-dim transpose
  const int addrA = (((quad * 2) & 3) * 16 + l15) * 4;
  const int addrB = (((quad * 2 + 1) & 3) * 16 + l15) * 4;

  const int nt = 2 * qt + 2;
  // prefetch tile 0
  gload_lds16(&k_sm[tid * 8], kgb);
  gload_lds16(&k_sm[tid * 8 + 2048], kgb + (size_t)32 * N3);
  gload_lds16(&vt_sm[tid * 8], vgb);
  gload_lds16(&vt_sm[tid * 8 + 2048], vgb + (size_t)32 * S_);

  for (int t = 0; t < nt; t++) {
    __syncthreads();   // buf[t&1] staged; buf[(t+1)&1] readers done
    if (t + 1 < nt) {
      const int nb = ((t + 1) & 1) * 4096;
      const unsigned short* kgt = kgb + (size_t)(t + 1) * 64 * N3;
      const unsigned short* vgt = vgb + (t + 1) * 64;
      gload_lds16(&k_sm[nb + tid * 8], kgt);
      gload_lds16(&k_sm[nb + tid * 8 + 2048], kgt + (size_t)32 * N3);
      gload_lds16(&vt_sm[nb + tid * 8], vgt);
      gload_lds16(&vt_sm[nb + tid * 8 + 2048], vgt + (size_t)32 * S_);
    }

    const unsigned short* kb = &k_sm[(t & 1) * 4096];
    const unsigned short* vb = &vt_sm[(t & 1) * 4096];
    // fragment base pointers; mb stride is the constant 1024 elements
    const unsigned short* kb0 = kb + l15 * 64 + ((quad ^ sw) << 3);
    const unsigned short* kb1 = kb + l15 * 64 + (((4 + quad) ^ sw) << 3);
    const unsigned short* vb0 = vb + l15 * 64 + ((quad ^ sw) << 3);
    const unsigned short* vb1 = vb + l15 * 64 + (((4 + quad) ^ sw) << 3);

    // K fragments shared by both row groups
    bf16x8 kf0[4], kf1[4];
#pragma unroll
    for (int mb = 0; mb < 4; mb++) {
      kf0[mb] = *(const bf16x8*)&kb0[mb * 1024];
      kf1[mb] = *(const bf16x8*)&kb1[mb * 1024];
    }
    // V fragments shared by both row groups (ks = 0, 1)
    bf16x8 vf0[4], vf1[4];
#pragma unroll
    for (int mb = 0; mb < 4; mb++) {
      vf0[mb] = *(const bf16x8*)&vb0[mb * 1024];
      vf1[mb] = *(const bf16x8*)&vb1[mb * 1024];
    }

#pragma unroll
    for (int g = 0; g < 2; g++) {
      if (g == 0 && t + 1 >= nt) continue;   // group 0 skips the last tile
      const int qr = (g == 0) ? qrow0 : qrow1;

      // S^T = K Q^T : lane holds keys mb*16+quad*4+r for qrow = qr
      f32x4 s[4];
#pragma unroll
      for (int mb = 0; mb < 4; mb++) s[mb] = (f32x4){0.f, 0.f, 0.f, 0.f};
#pragma unroll
      for (int mb = 0; mb < 4; mb++) {
        s[mb] = __builtin_amdgcn_mfma_f32_16x16x32_bf16(kf0[mb], qf[g][0], s[mb], 0, 0, 0);
        s[mb] = __builtin_amdgcn_mfma_f32_16x16x32_bf16(kf1[mb], qf[g][1], s[mb], 0, 0, 0);
      }

      // P = exp2(S) (scale pre-folded); mask only on this group's diagonal
      if (t != nt - 2 + g) {
#pragma unroll
        for (int mb = 0; mb < 4; mb++)
#pragma unroll
          for (int r = 0; r < 4; r++)
            s[mb][r] = exp2f(s[mb][r]);
      } else {
        const int kq0 = t * 64 + quad * 4;
#pragma unroll
        for (int mb = 0; mb < 4; mb++)
#pragma unroll
          for (int r = 0; r < 4; r++) {
            const float e = exp2f(s[mb][r]);
            s[mb][r] = (kq0 + mb * 16 + r <= qr) ? e : 0.f;
          }
      }
#pragma unroll
      for (int mb = 0; mb < 4; mb++)
        lsum[g] += (s[mb][0] + s[mb][1]) + (s[mb][2] + s[mb][3]);

      // pack to bf16 pairs: pk[mb][x] = keys (mb*16+quad*4+2x, +2x+1)
      int pk[4][2];
#pragma unroll
      for (int mb = 0; mb < 4; mb++) {
        const unsigned u0 = __float_as_uint(s[mb][0]) + 0x8000u;
        const unsigned u1 = __float_as_uint(s[mb][1]) + 0x8000u;
        const unsigned u2 = __float_as_uint(s[mb][2]) + 0x8000u;
        const unsigned u3 = __float_as_uint(s[mb][3]) + 0x8000u;
        pk[mb][0] = (int)__builtin_amdgcn_perm(u1, u0, 0x07060302u);
        pk[mb][1] = (int)__builtin_amdgcn_perm(u3, u2, 0x07060302u);
      }

      // O^T += V^T P^T : per K-step ks (32 keys) build P^T B-fragment
      const bool hi = quad >= 2;   // m_src = 2ks + (quad>>1)
#pragma unroll
      for (int ks = 0; ks < 2; ks++) {
        const int m0 = 2 * ks, m1 = m0 + 1;
        const int f0a = __builtin_amdgcn_ds_bpermute(addrA, pk[m0][0]);
        const int f0b = __builtin_amdgcn_ds_bpermute(addrA, pk[m1][0]);
        const int f1a = __builtin_amdgcn_ds_bpermute(addrA, pk[m0][1]);
        const int f1b = __builtin_amdgcn_ds_bpermute(addrA, pk[m1][1]);
        const int f2a = __builtin_amdgcn_ds_bpermute(addrB, pk[m0][0]);
        const int f2b = __builtin_amdgcn_ds_bpermute(addrB, pk[m1][0]);
        const int f3a = __builtin_amdgcn_ds_bpermute(addrB, pk[m0][1]);
        const int f3b = __builtin_amdgcn_ds_bpermute(addrB, pk[m1][1]);
        i32x4 fr;
        fr.x = hi ? f0b : f0a;
        fr.y = hi ? f1b : f1a;
        fr.z = hi ? f2b : f2a;
        fr.w = hi ? f3b : f3a;
        const bf16x8 pfrag = __builtin_bit_cast(bf16x8, fr);
#pragma unroll
        for (int mb = 0; mb < 4; mb++) {
          const bf16x8 vf = (ks == 0) ? vf0[mb] : vf1[mb];
          o[g][mb] = __builtin_amdgcn_mfma_f32_16x16x32_bf16(vf, pfrag, o[g][mb], 0, 0, 0);
        }
      }
    }
  }

  // normalize + write per group
#pragma unroll
  for (int g = 0; g < 2; g++) {
    float l = lsum[g];
    l += __shfl_xor(l, 16);
    l += __shfl_xor(l, 32);
    const float inv = 1.0f / l;
    const size_t grow = (size_t)(b * S_ + ((g == 0) ? qrow0 : qrow1));
#pragma unroll
    for (int mb = 0; mb < 4; mb++) {
      ushort4 w;
      w.x = f2bf(o[g][mb][0] * inv);
      w.y = f2bf(o[g][mb][1] * inv);
      w.z = f2bf(o[g][mb][2] * inv);
      w.w = f2bf(o[g][mb][3] * inv);
      *(ushort4*)&attnout[grow * DM + h * HD + mb * 16 + quad * 4] = w;
    }
  }
}

// ---------------------------------------------------------------------------
extern "C" void kernel_launch(void* const* d_in, const int* in_sizes, int n_in,
                              void* d_out, int out_size, void* d_ws, size_t ws_size,
                              hipStream_t stream) {
  const float* query = (const float*)d_in[0];   // [4096][1024]
  const float* w_in  = (const float*)d_in[1];   // [1024][3072]
  const float* w_out = (const float*)d_in[2];   // [1024][1024]
  float* out = (float*)d_out;                   // [4096][1024] fp32

  char* ws = (char*)d_ws;
  unsigned short* qbf     = (unsigned short*)(ws);                 //  8 MB (dead after gemm1)
  unsigned short* vT      = (unsigned short*)(ws);                 //  8 MB (aliases qbf)
  unsigned short* w_in_t  = (unsigned short*)(ws + 8388608);       //  6 MB [3072][1024]
  unsigned short* w_out_t = (unsigned short*)(ws + 14680064);      //  2 MB [1024][1024]
  unsigned short* qkv     = (unsigned short*)(ws + 16777216);      // 24 MB [4096][3072]
  unsigned short* attn    = (unsigned short*)(ws + 41943040);      //  8 MB [4096][1024]

  // 1. convert query fp32 -> bf16
  f32_to_bf16_vec<<<dim3(M_ * DM / 1024), dim3(256), 0, stream>>>(
      (const float4*)query, qbf, M_ * DM / 4);
  // 2. transpose+convert weights; fold 0.125*log2e into W_in Q-columns
  transpose_f32_bf16<<<dim3(N3 / 32, DM / 32), dim3(32, 8), 0, stream>>>(
      w_in, w_in_t, DM, N3, DM, SCALE_LOG2E);
  transpose_f32_bf16<<<dim3(DM / 32, DM / 32), dim3(32, 8), 0, stream>>>(
      w_out, w_out_t, DM, DM, 0, 1.0f);
  // 3. qkv = query @ W_in   [4096][3072] bf16 (Q slice pre-scaled)
  gemm_abt<1><<<dim3(N3 / 128, M_ / 128), dim3(256), 0, stream>>>(qbf, w_in_t, qkv, M_, N3, DM);
  // 4. vT[b][h][d][s] from qkv V slice (qbf is dead now)
  transpose_v<<<dim3(DM / 32, M_ / 32), dim3(32, 8), 0, stream>>>(qkv, vT);
  // 5. fused causal attention -> attn [4096][1024] bf16
  attn_fused5<<<dim3(16, NH, B_), dim3(256), 0, stream>>>(qkv, vT, attn);
  // 6. out = attn @ W_out   [4096][1024] fp32
  gemm_abt<0><<<dim3(DM / 128, M_ / 128), dim3(256), 0, stream>>>(attn, w_out_t, out, M_, DM, DM);
}

// Round 3
// 206.467 us; speedup vs baseline: 1.0412x; 1.0412x over previous
//
#include <hip/hip_runtime.h>

// ---------------------------------------------------------------------------
// MultiHeadedAttention: B=2, S=2048, Dm=1024, H=16, hd=64
// R6: finer barrier domains at constant TLP:
//  - 256-thread blocks (4 waves), grid (32,NH,B) = 1024 blocks = 4 blocks/CU
//    -> 16 waves/CU (same as R3/R4) but barriers park 4 waves, not 8
//  - waves 0-1 own 32-row group j, waves 2-3 own group 63-j: per-block work
//    constant (~66 wave-tile units), co-resident blocks share loop length
//  - inner loop identical to R4 (verified); scale*log2e pre-folded into W_in
//  - double-buffered K/V staging (2 rows/thread), ONE barrier per key-tile
//  - S^T=mfma(K,Q), O^T=mfma(V^T,P^T), P transpose via ds_bpermute
// ---------------------------------------------------------------------------

typedef __bf16 bf16x8 __attribute__((ext_vector_type(8)));
typedef float f32x4 __attribute__((ext_vector_type(4)));
typedef int i32x4 __attribute__((ext_vector_type(4)));

#define B_   2
#define S_   2048
#define DM   1024
#define NH   16
#define HD   64
#define N3   3072
#define M_   4096   // B_*S_

// 0.125 (1/sqrt(64)) * log2(e) -- folded into W_in Q-columns on host side
#define SCALE_LOG2E 0.180336884f

__device__ __forceinline__ unsigned short f2bf(float f) {
  unsigned int u = __float_as_uint(f);
  u += 0x7fffu + ((u >> 16) & 1u);   // round-to-nearest-even
  return (unsigned short)(u >> 16);
}

__device__ __forceinline__ void gload_lds16(void* lds, const void* g) {
  __builtin_amdgcn_global_load_lds(
      (__attribute__((address_space(1))) void*)g,
      (__attribute__((address_space(3))) void*)lds, 16, 0, 0);
}

// ---------------- fp32 -> bf16 elementwise (query) -------------------------
__global__ __launch_bounds__(256) void f32_to_bf16_vec(
    const float4* __restrict__ in, unsigned short* __restrict__ out, int n4) {
  int i = blockIdx.x * 256 + threadIdx.x;
  if (i < n4) {
    float4 v = in[i];
    ushort4 o;
    o.x = f2bf(v.x); o.y = f2bf(v.y); o.z = f2bf(v.z); o.w = f2bf(v.w);
    *(ushort4*)(&out[(size_t)i * 4]) = o;
  }
}

// ------- fp32 [R][C] -> bf16 [C][R] transpose (weights), row-scaled --------
// output rows < scale_rows get multiplied by scale (f32, before rounding)
__global__ __launch_bounds__(256) void transpose_f32_bf16(
    const float* __restrict__ in, unsigned short* __restrict__ out, int R, int C,
    int scale_rows, float scale) {
  __shared__ float tile[32][33];
  const int tx = threadIdx.x, ty = threadIdx.y;
  const int x = blockIdx.x * 32 + tx;
  const int y0 = blockIdx.y * 32;
#pragma unroll
  for (int j = 0; j < 32; j += 8)
    tile[ty + j][tx] = in[(size_t)(y0 + ty + j) * C + x];
  __syncthreads();
  const int ox = y0 + tx;
  const int oy0 = blockIdx.x * 32;
#pragma unroll
  for (int j = 0; j < 32; j += 8) {
    const int orow = oy0 + ty + j;
    float v = tile[tx][ty + j];
    if (orow < scale_rows) v *= scale;
    out[(size_t)orow * R + ox] = f2bf(v);
  }
}

// ---------------- V slice of qkv -> vT[b][h][d][s] (bf16) ------------------
__global__ __launch_bounds__(256) void transpose_v(
    const unsigned short* __restrict__ qkv, unsigned short* __restrict__ vT) {
  __shared__ unsigned short tile[32][33];
  const int tx = threadIdx.x, ty = threadIdx.y;
  const int c0 = blockIdx.x * 32;   // v-dim 0..1023
  const int r0 = blockIdx.y * 32;   // token 0..4095
#pragma unroll
  for (int j = 0; j < 32; j += 8)
    tile[ty + j][tx] = qkv[(size_t)(r0 + ty + j) * N3 + 2 * DM + c0 + tx];
  __syncthreads();
  const int b = r0 >> 11;
  const int srow = (r0 & 2047);
  const int head = c0 >> 6;
#pragma unroll
  for (int j = 0; j < 32; j += 8) {
    const int d = (c0 & 63) + ty + j;
    vT[(size_t)((b * NH + head) * HD + d) * S_ + srow + tx] = tile[tx][ty + j];
  }
}

// ---------------- GEMM: C[M][N] = A[M][K] @ Bt[N][K]^T ---------------------
template <int OUT_BF16>
__global__ __launch_bounds__(256) void gemm_abt(
    const unsigned short* __restrict__ A, const unsigned short* __restrict__ Bt,
    void* __restrict__ Cv, int M, int N, int K) {
  __shared__ __align__(16) unsigned short a_sm[128 * 32];
  __shared__ __align__(16) unsigned short b_sm[128 * 32];
  const int tid = threadIdx.x;
  const int lane = tid & 63, wave = tid >> 6;
  const int quad = lane >> 4, l15 = lane & 15;
  const int row0 = blockIdx.y * 128, col0 = blockIdx.x * 128;
  const int wm = (wave >> 1) * 64, wn = (wave & 1) * 64;

  f32x4 acc[4][4];
#pragma unroll
  for (int i = 0; i < 4; i++)
#pragma unroll
    for (int j = 0; j < 4; j++) acc[i][j] = (f32x4){0.f, 0.f, 0.f, 0.f};

  const int e0 = tid * 8;

  for (int k0 = 0; k0 < K; k0 += 32) {
    __syncthreads();
#pragma unroll
    for (int i = 0; i < 2; i++) {
      int e = e0 + i * 2048;
      int r = e >> 5, c = e & 31;
      gload_lds16(&a_sm[e], &A[(size_t)(row0 + r) * K + k0 + c]);
      gload_lds16(&b_sm[e], &Bt[(size_t)(col0 + r) * K + k0 + c]);
    }
    __syncthreads();

    bf16x8 af[4], bfb[4];
#pragma unroll
    for (int i = 0; i < 4; i++) {
      af[i]  = *(const bf16x8*)&a_sm[(wm + i * 16 + l15) * 32 + quad * 8];
      bfb[i] = *(const bf16x8*)&b_sm[(wn + i * 16 + l15) * 32 + quad * 8];
    }
#pragma unroll
    for (int i = 0; i < 4; i++)
#pragma unroll
      for (int j = 0; j < 4; j++)
        acc[i][j] = __builtin_amdgcn_mfma_f32_16x16x32_bf16(af[i], bfb[j], acc[i][j], 0, 0, 0);
  }

#pragma unroll
  for (int i = 0; i < 4; i++) {
#pragma unroll
    for (int j = 0; j < 4; j++) {
#pragma unroll
      for (int r = 0; r < 4; r++) {
        const int row = row0 + wm + i * 16 + quad * 4 + r;
        const int col = col0 + wn + j * 16 + l15;
        const float v = acc[i][j][r];
        if (OUT_BF16)
          ((unsigned short*)Cv)[(size_t)row * N + col] = f2bf(v);
        else
          ((float*)Cv)[(size_t)row * N + col] = v;
      }
    }
  }
}

// ---------------- fused causal attention v6 --------------------------------
// grid (32, NH, B), 256 threads (4 waves). Waves 0-1: 32-row group j;
// waves 2-3: 32-row group 63-j. Every block: ~66 wave-tile units (constant).
// 4 blocks/CU -> 16 waves/CU in 4 independent barrier domains.
// Scores arrive pre-scaled by 0.125*log2e (folded into W_in).
__global__ __launch_bounds__(256, 4) void attn_fused6(
    const unsigned short* __restrict__ qkv,
    const unsigned short* __restrict__ vT,
    unsigned short* __restrict__ attnout) {
  const int h = blockIdx.y, b = blockIdx.z;
  const int j = blockIdx.x;                     // 0..31
  const int tid = threadIdx.x;
  const int lane = tid & 63, wave = tid >> 6;   // wave 0..3
  const int quad = lane >> 4, l15 = lane & 15;
  const int sw = l15 & 7;

  __shared__ __align__(16) unsigned short k_sm[2 * 4096];   // [buf][64 keys][64 d]
  __shared__ __align__(16) unsigned short vt_sm[2 * 4096];  // [buf][64 d][64 keys]

  // waves 0,1 -> 32-row group j; waves 2,3 -> group 63-j
  const int grp = (wave < 2) ? j : (63 - j);
  const int wrow0 = grp * 32 + (wave & 1) * 16;   // wave's min q row
  const int qrow = wrow0 + l15;                   // this lane's q row

  // Q fragment (B-operand for S^T, A/B layouts are lane-symmetric)
  bf16x8 qf[2];
  {
    const unsigned short* qp = qkv + (size_t)(b * S_ + qrow) * N3 + h * HD + quad * 8;
    qf[0] = *(const bf16x8*)qp;
    qf[1] = *(const bf16x8*)(qp + 32);
  }

  f32x4 o[4];   // O^T accumulator: d = mb*16+quad*4+r, col = qrow
#pragma unroll
  for (int n = 0; n < 4; n++) o[n] = (f32x4){0.f, 0.f, 0.f, 0.f};
  float lsum = 0.f;

  // staging: thread stages rows r0s and r0s+32 (16B each); phys chunk tid&7
  // holds logical chunk (tid&7)^(r0s&7) (XOR swizzle, conflict-free b128)
  const int r0s = tid >> 3;                       // 0..31
  const int gch = ((tid & 7) ^ (r0s & 7)) * 8;
  const unsigned short* kgb = qkv + (size_t)(b * S_ + r0s) * N3 + DM + h * HD + gch;
  const unsigned short* vgb = vT + (size_t)((b * NH + h) * HD + r0s) * S_ + gch;

  // bpermute pull addresses (byte addr = src_lane*4), quad-dim transpose
  const int addrA = (((quad * 2) & 3) * 16 + l15) * 4;
  const int addrB = (((quad * 2 + 1) & 3) * 16 + l15) * 4;

  // key tiles needed by the high group (covers the low group too)
  const int nt = (((63 - j) * 32 + 31) >> 6) + 1;

  // prefetch tile 0
  gload_lds16(&k_sm[tid * 8], kgb);
  gload_lds16(&k_sm[tid * 8 + 2048], kgb + (size_t)32 * N3);
  gload_lds16(&vt_sm[tid * 8], vgb);
  gload_lds16(&vt_sm[tid * 8 + 2048], vgb + (size_t)32 * S_);

  for (int t = 0; t < nt; t++) {
    __syncthreads();   // buf[t&1] staged; buf[(t+1)&1] readers done
    if (t + 1 < nt) {
      const int nb = ((t + 1) & 1) * 4096;
      const unsigned short* kgt = kgb + (size_t)(t + 1) * 64 * N3;
      const unsigned short* vgt = vgb + (t + 1) * 64;
      gload_lds16(&k_sm[nb + tid * 8], kgt);
      gload_lds16(&k_sm[nb + tid * 8 + 2048], kgt + (size_t)32 * N3);
      gload_lds16(&vt_sm[nb + tid * 8], vgt);
      gload_lds16(&vt_sm[nb + tid * 8 + 2048], vgt + (size_t)32 * S_);
    }
    if (t * 64 > wrow0 + 15) continue;   // tile fully masked for this wave

    const unsigned short* kb = &k_sm[(t & 1) * 4096];
    const unsigned short* vb = &vt_sm[(t & 1) * 4096];

    // S^T = K Q^T : D[m=key][n=qrow]; lane holds keys mb*16+quad*4+r, qrow=l15
    f32x4 s[4];
#pragma unroll
    for (int mb = 0; mb < 4; mb++) s[mb] = (f32x4){0.f, 0.f, 0.f, 0.f};
#pragma unroll
    for (int mb = 0; mb < 4; mb++) {
      const int ro = (mb * 16 + l15) * 64;
      bf16x8 kf0 = *(const bf16x8*)&kb[ro + ((quad ^ sw) << 3)];
      bf16x8 kf1 = *(const bf16x8*)&kb[ro + (((4 + quad) ^ sw) << 3)];
      s[mb] = __builtin_amdgcn_mfma_f32_16x16x32_bf16(kf0, qf[0], s[mb], 0, 0, 0);
      s[mb] = __builtin_amdgcn_mfma_f32_16x16x32_bf16(kf1, qf[1], s[mb], 0, 0, 0);
    }

    // P = exp2(S) (scale pre-folded); mask only when tile straddles diagonal
    if (t * 64 + 63 <= wrow0) {
#pragma unroll
      for (int mb = 0; mb < 4; mb++)
#pragma unroll
        for (int r = 0; r < 4; r++)
          s[mb][r] = exp2f(s[mb][r]);
    } else {
      const int kq0 = t * 64 + quad * 4;
#pragma unroll
      for (int mb = 0; mb < 4; mb++)
#pragma unroll
        for (int r = 0; r < 4; r++) {
          const float e = exp2f(s[mb][r]);
          s[mb][r] = (kq0 + mb * 16 + r <= qrow) ? e : 0.f;
        }
    }
#pragma unroll
    for (int mb = 0; mb < 4; mb++)
      lsum += (s[mb][0] + s[mb][1]) + (s[mb][2] + s[mb][3]);

    // pack to bf16 pairs: pk[mb][x] = keys (mb*16+quad*4+2x, +2x+1)
    int pk[4][2];
#pragma unroll
    for (int mb = 0; mb < 4; mb++) {
      const unsigned u0 = __float_as_uint(s[mb][0]) + 0x8000u;
      const unsigned u1 = __float_as_uint(s[mb][1]) + 0x8000u;
      const unsigned u2 = __float_as_uint(s[mb][2]) + 0x8000u;
      const unsigned u3 = __float_as_uint(s[mb][3]) + 0x8000u;
      pk[mb][0] = (int)__builtin_amdgcn_perm(u1, u0, 0x07060302u);
      pk[mb][1] = (int)__builtin_amdgcn_perm(u3, u2, 0x07060302u);
    }

    // O^T += V^T P^T : per K-step ks (32 keys) build P^T B-fragment
    const bool hi = quad >= 2;   // m_src = 2ks + (quad>>1)
#pragma unroll
    for (int ks = 0; ks < 2; ks++) {
      const int m0 = 2 * ks, m1 = m0 + 1;
      const int f0a = __builtin_amdgcn_ds_bpermute(addrA, pk[m0][0]);
      const int f0b = __builtin_amdgcn_ds_bpermute(addrA, pk[m1][0]);
      const int f1a = __builtin_amdgcn_ds_bpermute(addrA, pk[m0][1]);
      const int f1b = __builtin_amdgcn_ds_bpermute(addrA, pk[m1][1]);
      const int f2a = __builtin_amdgcn_ds_bpermute(addrB, pk[m0][0]);
      const int f2b = __builtin_amdgcn_ds_bpermute(addrB, pk[m1][0]);
      const int f3a = __builtin_amdgcn_ds_bpermute(addrB, pk[m0][1]);
      const int f3b = __builtin_amdgcn_ds_bpermute(addrB, pk[m1][1]);
      i32x4 fr;
      fr.x = hi ? f0b : f0a;
      fr.y = hi ? f1b : f1a;
      fr.z = hi ? f2b : f2a;
      fr.w = hi ? f3b : f3a;
      const bf16x8 pfrag = __builtin_bit_cast(bf16x8, fr);
#pragma unroll
      for (int mb = 0; mb < 4; mb++) {
        const int ro = (mb * 16 + l15) * 64;
        bf16x8 vf = *(const bf16x8*)&vb[ro + (((ks * 4 + quad) ^ sw) << 3)];
        o[mb] = __builtin_amdgcn_mfma_f32_16x16x32_bf16(vf, pfrag, o[mb], 0, 0, 0);
      }
    }
  }

  // normalize + write (O^T: lane has 4 consecutive d per mb for its qrow)
  float l = lsum;
  l += __shfl_xor(l, 16);
  l += __shfl_xor(l, 32);
  const float inv = 1.0f / l;
  const size_t grow = (size_t)(b * S_ + qrow);
#pragma unroll
  for (int mb = 0; mb < 4; mb++) {
    ushort4 w;
    w.x = f2bf(o[mb][0] * inv);
    w.y = f2bf(o[mb][1] * inv);
    w.z = f2bf(o[mb][2] * inv);
    w.w = f2bf(o[mb][3] * inv);
    *(ushort4*)&attnout[grow * DM + h * HD + mb * 16 + quad * 4] = w;
  }
}

// ---------------------------------------------------------------------------
extern "C" void kernel_launch(void* const* d_in, const int* in_sizes, int n_in,
                              void* d_out, int out_size, void* d_ws, size_t ws_size,
                              hipStream_t stream) {
  const float* query = (const float*)d_in[0];   // [4096][1024]
  const float* w_in  = (const float*)d_in[1];   // [1024][3072]
  const float* w_out = (const float*)d_in[2];   // [1024][1024]
  float* out = (float*)d_out;                   // [4096][1024] fp32

  char* ws = (char*)d_ws;
  unsigned short* qbf     = (unsigned short*)(ws);                 //  8 MB (dead after gemm1)
  unsigned short* vT      = (unsigned short*)(ws);                 //  8 MB (aliases qbf)
  unsigned short* w_in_t  = (unsigned short*)(ws + 8388608);       //  6 MB [3072][1024]
  unsigned short* w_out_t = (unsigned short*)(ws + 14680064);      //  2 MB [1024][1024]
  unsigned short* qkv     = (unsigned short*)(ws + 16777216);      // 24 MB [4096][3072]
  unsigned short* attn    = (unsigned short*)(ws + 41943040);      //  8 MB [4096][1024]

  // 1. convert query fp32 -> bf16
  f32_to_bf16_vec<<<dim3(M_ * DM / 1024), dim3(256), 0, stream>>>(
      (const float4*)query, qbf, M_ * DM / 4);
  // 2. transpose+convert weights; fold 0.125*log2e into W_in Q-columns
  transpose_f32_bf16<<<dim3(N3 / 32, DM / 32), dim3(32, 8), 0, stream>>>(
      w_in, w_in_t, DM, N3, DM, SCALE_LOG2E);
  transpose_f32_bf16<<<dim3(DM / 32, DM / 32), dim3(32, 8), 0, stream>>>(
      w_out, w_out_t, DM, DM, 0, 1.0f);
  // 3. qkv = query @ W_in   [4096][3072] bf16 (Q slice pre-scaled)
  gemm_abt<1><<<dim3(N3 / 128, M_ / 128), dim3(256), 0, stream>>>(qbf, w_in_t, qkv, M_, N3, DM);
  // 4. vT[b][h][d][s] from qkv V slice (qbf is dead now)
  transpose_v<<<dim3(DM / 32, M_ / 32), dim3(32, 8), 0, stream>>>(qkv, vT);
  // 5. fused causal attention -> attn [4096][1024] bf16
  attn_fused6<<<dim3(32, NH, B_), dim3(256), 0, stream>>>(qkv, vT, attn);
  // 6. out = attn @ W_out   [4096][1024] fp32
  gemm_abt<0><<<dim3(DM / 128, M_ / 128), dim3(256), 0, stream>>>(attn, w_out_t, out, M_, DM, DM);
}